// Round 1
// baseline (382.103 us; speedup 1.0000x reference)
//
#include <hip/hip_runtime.h>
#include <math.h>

#define W    3072
#define HH   3072
#define HOUT 3060       // HH - 12 (valid conv output for 13x13 kernel)
#define TW   64         // output cols per block
#define TH   56         // output rows per block (56 = 4 waves x 14 rows)
#define XR   68         // xt rows = TH + 12
#define XTS  76         // xt col stride (even -> float2/float4 aligned)
#define RPW  7          // row-pairs per wave (14 rows)
#define SVT  154        // vt row-pair stride in words (76 col-pairs*2 + 2 pad, even)
#define VTW  (RPW*SVT)  // per-wave vt words = 1078

typedef float f2 __attribute__((ext_vector_type(2)));

struct HessTaps { float a[13]; float bb[13]; float m[13]; float n[13]; };

__device__ __forceinline__ f2 pk_fma(f2 a, f2 b, f2 c) {
#if defined(__has_builtin) && __has_builtin(__builtin_elementwise_fma)
  return __builtin_elementwise_fma(a, b, c);   // -> v_pk_fma_f32 (IEEE fp32 per half)
#else
  f2 r; r.x = fmaf(a.x, b.x, c.x); r.y = fmaf(a.y, b.y, c.y); return r;
#endif
}

// ---- per-block reduction -> one f64 atomic ---------------------------------
__device__ __forceinline__ void reduce_add(float v, double* acc) {
  __shared__ float red[8];
  #pragma unroll
  for (int o = 32; o > 0; o >>= 1) v += __shfl_down(v, o, 64);
  int lane = threadIdx.x & 63, wid = threadIdx.x >> 6;
  if (lane == 0) red[wid] = v;
  __syncthreads();
  if (threadIdx.x == 0) {
    float s = 0.f;
    int nw = (blockDim.x + 63) >> 6;
    for (int i = 0; i < nw; ++i) s += red[i];
    unsafeAtomicAdd(acc, (double)s);
  }
  __syncthreads();   // protect red[] for a subsequent call
}

// ---- guided-filter term, exact collapse: gf(x,x) == x  =>  sum |st - x| ----
__global__ __launch_bounds__(256) void gf_l1(const float* __restrict__ x,
                                             const float* __restrict__ st,
                                             double* acc) {
  const int n4 = (W * HH) / 4;
  int stride = gridDim.x * 256;
  float local = 0.f;
  for (int i = blockIdx.x * 256 + threadIdx.x; i < n4; i += stride) {
    float4 a = ((const float4*)x)[i];
    float4 b = ((const float4*)st)[i];
    local += fabsf(b.x - a.x) + fabsf(b.y - a.y)
           + fabsf(b.z - a.z) + fabsf(b.w - a.w);
  }
  reduce_add(local, &acc[0]);
}

// ---- sampled L1*map term ---------------------------------------------------
__global__ __launch_bounds__(256) void mse_sample(const float* __restrict__ T,
                                                  const float* __restrict__ G,
                                                  const float* __restrict__ M,
                                                  double* acc) {
  int idx = blockIdx.x * 256 + threadIdx.x;
  float local = 0.f;
  if (idx < 384 * 384) {
    int si = idx / 384, sj = idx - si * 384;
    int id = si * 8 * W + sj * 8;
    local = fabsf(T[id] - G[id]) * M[id];
  }
  reduce_add(local, &acc[2]);
}

// ---- Hessian + TV, both images via gridDim.z -------------------------------
// 64x56 output tile, 4 waves x 14 rows each. Both conv passes use packed fp32:
//  * V pass: lane p<38 owns col-pair (2p,2p+1) as float2 (ds_read_b64 from xt,
//    naturally aligned, stride 76). One chain covers all 76 cols -> no halo
//    chain. Output stored row-pair interleaved: vt[rp][c][parity].
//  * H pass: lane (rpl<7, cg) reads {row,row+1} pairs as single ds_read_b64
//    from the interleaved layout; 104 packed FMAs replace 208 scalar.
//  * H reads only vt rows the SAME wave wrote -> no __syncthreads between
//    V and H or between terms (same-wave LDS RAW is in-order). Only barriers:
//    after xt load and around the d-update.
// LDS: xt 68*76*4=20672 + vt 4*1078*4=17248 + red 32 = 37952 B -> 4 blocks/CU.
__global__ __launch_bounds__(256, 4) void hess_kernel(const float* __restrict__ Gnn,
                                                      const float* __restrict__ Lr,
                                                      const float* __restrict__ T,
                                                      double* acc, HessTaps tp) {
  __shared__ float xt[XR * XTS];
  __shared__ float vt[4 * VTW];
  const float* img = (blockIdx.z == 0) ? Gnn : Lr;
  int oy = blockIdx.y * TH, ox = blockIdx.x * TW;
  int t = threadIdx.x;
  int wv = t >> 6, ln = t & 63;    // wave id 0..3, lane 0..63

  // load xt (68 rows x 76 cols) as aligned float4 with edge masking
  for (int idx = t; idx < XR * 19; idx += 256) {
    int r = idx / 19, g = idx - r * 19;
    int gr = oy + r, gc = ox + 4 * g;
    float4 v = {0.f, 0.f, 0.f, 0.f};
    if (gr < HH) {
      const float* p = &img[(size_t)gr * W + gc];
      if (gc + 3 < W) v = *(const float4*)p;
      else {
        if (gc < W)     v.x = p[0];
        if (gc + 1 < W) v.y = p[1];
        if (gc + 2 < W) v.z = p[2];
      }
    }
    *(float4*)&xt[r * XTS + 4 * g] = v;
  }
  __syncthreads();

  float tvl = 0.f;   // TV accumulator
  float hl  = 0.f;   // Hessian accumulator

  // TV Dx term on x: |x(r,c) - x(r,c+1)|  (lanes contiguous -> free)
  {
    int gc = ox + ln;
    if (gc < W - 1) {
      #pragma unroll
      for (int i = 0; i < 14; ++i) {
        int r = wv * 14 + i;
        if (oy + r < HH)
          tvl += fabsf(xt[r * XTS + ln] - xt[r * XTS + ln + 1]);
      }
    }
  }

  // ---- V pass (packed over col-pairs), wave-local rows 14wv..14wv+13.
  // out row i needs xt rows (14wv+i)+0..12 -> window u in [0,26).
  #define VFIRST(TAP)                                                       \
    if (ln < 38) {                                                          \
      int r0 = wv * 14;                                                     \
      const f2* xp = (const f2*)&xt[r0 * XTS + 2 * ln];                     \
      f2 xv[26];                                                            \
      _Pragma("unroll")                                                     \
      for (int u = 0; u < 26; ++u) xv[u] = xp[u * (XTS / 2)];               \
      f2 o_[14];                                                            \
      _Pragma("unroll")                                                     \
      for (int i = 0; i < 14; ++i) o_[i] = (f2){0.f, 0.f};                  \
      _Pragma("unroll")                                                     \
      for (int u = 0; u < 26; ++u) {                                        \
        _Pragma("unroll")                                                   \
        for (int i = 0; i < 14; ++i) {                                      \
          int kk = u - i;                                                   \
          if (kk >= 0 && kk <= 12) {                                        \
            float tv_ = (TAP)[kk];                                          \
            o_[i] = pk_fma((f2){tv_, tv_}, xv[u], o_[i]);                   \
          }                                                                 \
        }                                                                   \
      }                                                                     \
      float* vw = &vt[wv * VTW + 4 * ln];                                   \
      _Pragma("unroll")                                                     \
      for (int i = 0; i < 14; ++i) {                                        \
        vw[(i >> 1) * SVT + (i & 1)]     = o_[i].x;   /* col 2p   */        \
        vw[(i >> 1) * SVT + (i & 1) + 2] = o_[i].y;   /* col 2p+1 */        \
      }                                                                     \
    }

  // ---- H pass (packed over row-pairs), reads SAME wave's vt rows.
  // lane = (rpl 0..6, cg 0..7); out rows (14wv+2rpl, +1), cols cg*8..cg*8+7.
  #define HSECOND(TAP, WGT)                                                 \
    {                                                                       \
      int rpl = ln >> 3, cg = ln & 7;                                       \
      if (rpl < 7) {                                                        \
        const f2* vp = (const f2*)&vt[wv * VTW + rpl * SVT + 16 * cg];      \
        f2 v2[20];                                                          \
        _Pragma("unroll")                                                   \
        for (int j = 0; j < 20; ++j) v2[j] = vp[j];                         \
        f2 o_[8];                                                           \
        _Pragma("unroll")                                                   \
        for (int jj = 0; jj < 8; ++jj) o_[jj] = (f2){0.f, 0.f};             \
        _Pragma("unroll")                                                   \
        for (int j = 0; j < 20; ++j) {                                      \
          _Pragma("unroll")                                                 \
          for (int jj = 0; jj < 8; ++jj) {                                  \
            int kk = j - jj;                                                \
            if (kk >= 0 && kk <= 12) {                                      \
              float tv_ = (TAP)[kk];                                        \
              o_[jj] = pk_fma((f2){tv_, tv_}, v2[j], o_[jj]);               \
            }                                                               \
          }                                                                 \
        }                                                                   \
        int gr0 = oy + wv * 14 + 2 * rpl;                                   \
        int gc0 = ox + cg * 8;                                              \
        float w0 = (gr0 < HOUT)     ? (WGT) : 0.f;                          \
        float w1 = (gr0 + 1 < HOUT) ? (WGT) : 0.f;                          \
        _Pragma("unroll")                                                   \
        for (int jj = 0; jj < 8; ++jj) {                                    \
          if (gc0 + jj < HOUT) {                                            \
            hl = fmaf(w0, fabsf(o_[jj].x), hl);                             \
            hl = fmaf(w1, fabsf(o_[jj].y), hl);                             \
          }                                                                 \
        }                                                                   \
      }                                                                     \
    }

  // term 1: conv(x, Gxx) = vert bb, horiz a    (no barrier between V and H)
  VFIRST(tp.bb);
  HSECOND(tp.a, 1.0f);

  // d = x - target (in place); all waves must be done reading xt first
  __syncthreads();
  for (int idx = t; idx < XR * 19; idx += 256) {
    int r = idx / 19, g = idx - r * 19;
    int gr = oy + r, gc = ox + 4 * g;
    float4 v = {0.f, 0.f, 0.f, 0.f};
    if (gr < HH) {
      const float* p = &T[(size_t)gr * W + gc];
      if (gc + 3 < W) v = *(const float4*)p;
      else {
        if (gc < W)     v.x = p[0];
        if (gc + 1 < W) v.y = p[1];
        if (gc + 2 < W) v.z = p[2];
      }
    }
    float4 cur = *(float4*)&xt[r * XTS + 4 * g];
    cur.x -= v.x; cur.y -= v.y; cur.z -= v.z; cur.w -= v.w;
    *(float4*)&xt[r * XTS + 4 * g] = cur;
  }
  __syncthreads();

  // TV Dy term on d: |d(r,c) - d(r+1,c)|, r < HH-1
  {
    int gc = ox + ln;
    if (gc < W) {
      #pragma unroll
      for (int i = 0; i < 14; ++i) {
        int r = wv * 14 + i;
        if (oy + r < HH - 1)
          tvl += fabsf(xt[r * XTS + ln] - xt[(r + 1) * XTS + ln]);
      }
    }
  }

  // term 2: conv(d, Gyy) = vert a, horiz bb
  VFIRST(tp.a);
  HSECOND(tp.bb, 1.0f);

  // term 3: conv(d, Gxy) = vert m, horiz n, weight 2 (isotropic)
  VFIRST(tp.m);
  HSECOND(tp.n, 2.0f);

  reduce_add(tvl, &acc[1]);
  reduce_add(hl, &acc[3]);
}

// ---- combine ---------------------------------------------------------------
__global__ void finalize_kernel(const double* acc, float* out) {
  out[0] = (float)(acc[0] + acc[2] + 0.1 * acc[1] + 0.5 * acc[3]);
}

extern "C" void kernel_launch(void* const* d_in, const int* in_sizes, int n_in,
                              void* d_out, int out_size, void* d_ws, size_t ws_size,
                              hipStream_t stream) {
  const float* xraw = (const float*)d_in[0];   // outputGNNraw
  const float* gnn  = (const float*)d_in[1];   // outputGNN
  const float* lr   = (const float*)d_in[2];   // outputLR
  const float* st   = (const float*)d_in[3];   // smoothedTarget
  const float* tg   = (const float*)d_in[4];   // targets
  const float* mp   = (const float*)d_in[5];   // map
  float* out = (float*)d_out;

  double* acc = (double*)d_ws;
  hipMemsetAsync(d_ws, 0, 32, stream);   // zero the 4 f64 accumulators

  // Guided-filter term: gf(x,x) == x exactly (A==1, b==0 bitwise), so the
  // term reduces to sum |st - x|. (Verified in earlier rounds: full pipeline
  // matched the reference with absmax 0.0.)
  gf_l1<<<dim3(2048), 256, 0, stream>>>(xraw, st, acc);

  mse_sample<<<dim3((384 * 384 + 255) / 256), 256, 0, stream>>>(tg, gnn, mp, acc);

  // separable Hessian-of-Gaussian taps (sigma=1, t = -6..6):
  //   Gxx[i,j] = bb(i)*a(j); Gyy[i,j] = a(i)*bb(j); Gxy[i,j] = m(i)*n(j)
  HessTaps tp;
  const double PI2 = 6.283185307179586476925287;
  for (int k = 0; k < 13; ++k) {
    double tt = (double)(k - 6);
    double g = exp(-0.5 * tt * tt);
    tp.a[k]  = (float)((tt * tt - 1.0) * g / PI2);
    tp.bb[k] = (float)g;
    tp.m[k]  = (float)(tt * g / PI2);
    tp.n[k]  = (float)(tt * g);
  }
  // grid: 48 x-tiles (48*64=3072 cols), 55 y-tiles (55*56=3080 >= 3072 rows,
  // per-row masks handle the overhang), z = {GNN, LR}
  hess_kernel<<<dim3(48, 55, 2), 256, 0, stream>>>(gnn, lr, tg, acc, tp);

  finalize_kernel<<<1, 1, 0, stream>>>(acc, out);
}